// Round 6
// baseline (411.231 us; speedup 1.0000x reference)
//
#include <hip/hip_runtime.h>
#include <math.h>

#define NH 8
#define HD 64
#define NSEQ 1024
#define DMODEL 512
#define F3 1536
#define NTOK 16384
#define BH 128    // (B*T)*NH = 16*8
#define KVP 72    // attn K/V LDS pitch (bf16)
#define TP 136    // qkv epilogue transpose pitch (bf16)
#define QSCALE 0.1803368867f  // 0.125 * log2(e), folded into q; p = exp2(s')

typedef __attribute__((ext_vector_type(8))) short bf16x8;
typedef __attribute__((ext_vector_type(4))) float f32x4;
#define MFMA16(a, b, c) __builtin_amdgcn_mfma_f32_16x16x32_bf16(a, b, c, 0, 0, 0)

typedef unsigned short ushort_t;

__device__ __forceinline__ float freq_of(int j) {
    return 3.14159265358979323846f * (1.0f + (float)j * (127.0f / 15.0f));
}
__device__ __forceinline__ unsigned short bf16_hi(float x) {
    unsigned u = __builtin_bit_cast(unsigned, x);
    return (unsigned short)(u >> 16);   // truncation split; residual goes to lo
}
__device__ __forceinline__ unsigned short bf16_rtn(float x) {
    unsigned u = __builtin_bit_cast(unsigned, x);
    return (unsigned short)((u + 0x7FFF + ((u >> 16) & 1)) >> 16);  // round-nearest-even
}
__device__ __forceinline__ float bf16_tofloat(unsigned short h) {
    unsigned u = ((unsigned)h) << 16;
    return __builtin_bit_cast(float, u);
}
__device__ __forceinline__ void gld_lds16(unsigned short* lds_dst, const unsigned short* gsrc) {
    __builtin_amdgcn_global_load_lds(
        (const __attribute__((address_space(1))) unsigned int*)gsrc,
        (__attribute__((address_space(3))) unsigned int*)lds_dst,
        16, 0, 0);
}
// LDS bank swizzle key for row r (applies to 16-B col-groups)
__device__ __forceinline__ int swz(int r) { return (r & 3) ^ ((r >> 2) & 3); }

// ---------------- Kernel 0a: split fp32 -> bf16 hi/lo (trunc) ----------------
__global__ __launch_bounds__(256) void split_kernel(
        const float* __restrict__ src, unsigned short* __restrict__ hi,
        unsigned short* __restrict__ lo) {
    const int i = blockIdx.x * 256 + threadIdx.x;
    const float4 v = ((const float4*)src)[i];
    ushort4 h, l;
    h.x = bf16_hi(v.x); l.x = bf16_hi(v.x - bf16_tofloat(h.x));
    h.y = bf16_hi(v.y); l.y = bf16_hi(v.y - bf16_tofloat(h.y));
    h.z = bf16_hi(v.z); l.z = bf16_hi(v.z - bf16_tofloat(h.z));
    h.w = bf16_hi(v.w); l.w = bf16_hi(v.w - bf16_tofloat(h.w));
    ((ushort4*)hi)[i] = h;
    ((ushort4*)lo)[i] = l;
}
// ---------------- Kernel 0b: fp32 -> bf16 RTN single plane ----------------
__global__ __launch_bounds__(256) void cvt_kernel(
        const float* __restrict__ src, unsigned short* __restrict__ dst) {
    const int i = blockIdx.x * 256 + threadIdx.x;
    const float4 v = ((const float4*)src)[i];
    ((ushort4*)dst)[i] = make_ushort4(bf16_rtn(v.x), bf16_rtn(v.y),
                                      bf16_rtn(v.z), bf16_rtn(v.w));
}

// ---- pipelined GEMM core: 128m x 256f tile, BK=32, 256 thr, wave 64m x 128f ----
// PLANES=2: A hi/lo (2-term, exact in A), B single bf16. PLANES=1: both single.
// 2-stage ping-pong via global_load_lds; XOR-swizzled stage layout so frag
// ds_read_b128 is 2-way (free) instead of 8-way banked.
template<int PLANES>
__device__ __forceinline__ void gemm_pipe(
        const unsigned short* __restrict__ a_hi, const unsigned short* __restrict__ a_lo,
        const unsigned short* __restrict__ b_bf,
        char* lds, int m0, int f0, int t, f32x4 acc[4][8]) {
    const int w = t >> 6, lane = t & 63, l15 = lane & 15, quad = lane >> 4;
    const int mw = (w & 1) * 64, nw = (w >> 1) * 128;
    const int STAGE = (PLANES == 2) ? 16384 : 12288;   // elements per stage
    const int BOFF  = (PLANES == 2) ? 8192 : 4096;     // B base in stage (elements)
    const int PERW  = (PLANES == 2) ? 8 : 6;           // chunks per wave (32 or 24 total)
    const int rsub = lane >> 2;                         // row within 16-row chunk
    const int gg = (lane & 3) ^ swz(rsub);              // swizzled global col-group

    auto issue = [&](int kt, int stage) {
        unsigned short* S = (unsigned short*)lds + (size_t)stage * STAGE;
        const int k0 = kt * 32;
        #pragma unroll
        for (int ii = 0; ii < PERW; ii++) {
            const int idx = w * PERW + ii;
            const unsigned short* src;
            unsigned short* dst;
            int row0;
            if (PLANES == 2) {
                if (idx < 8)       { src = a_hi; row0 = m0 + idx * 16;        dst = S + idx * 512; }
                else if (idx < 16) { src = a_lo; row0 = m0 + (idx - 8) * 16;  dst = S + 4096 + (idx - 8) * 512; }
                else               { src = b_bf; row0 = f0 + (idx - 16) * 16; dst = S + 8192 + (idx - 16) * 512; }
            } else {
                if (idx < 8)       { src = a_hi; row0 = m0 + idx * 16;        dst = S + idx * 512; }
                else               { src = b_bf; row0 = f0 + (idx - 8) * 16;  dst = S + 4096 + (idx - 8) * 512; }
            }
            gld_lds16(dst, src + (size_t)(row0 + rsub) * DMODEL + k0 + gg * 8);
        }
    };

    issue(0, 0);
    for (int kt = 0; kt < 16; kt++) {
        __syncthreads();                 // drains stage-kt loads (in flight since kt-1)
        if (kt < 15) issue(kt + 1, (kt + 1) & 1);
        const unsigned short* S = (const unsigned short*)lds + (size_t)(kt & 1) * STAGE;
        bf16x8 ah[4], al[4], bb[8];
        #pragma unroll
        for (int mt = 0; mt < 4; mt++) {
            const int r = mw + mt * 16 + l15;
            const int slot = quad ^ swz(r);
            ah[mt] = *(const bf16x8*)&S[r * 32 + slot * 8];
            if (PLANES == 2) al[mt] = *(const bf16x8*)&S[4096 + r * 32 + slot * 8];
        }
        #pragma unroll
        for (int nt = 0; nt < 8; nt++) {
            const int r = nw + nt * 16 + l15;
            const int slot = quad ^ swz(r);
            bb[nt] = *(const bf16x8*)&S[BOFF + r * 32 + slot * 8];
        }
        #pragma unroll
        for (int mt = 0; mt < 4; mt++)
            #pragma unroll
            for (int nt = 0; nt < 8; nt++) {
                acc[mt][nt] = MFMA16(ah[mt], bb[nt], acc[mt][nt]);
                if (PLANES == 2) acc[mt][nt] = MFMA16(al[mt], bb[nt], acc[mt][nt]);
            }
    }
    __syncthreads();                     // stage LDS free for epilogue reuse
}

// ---------------- Kernel 1: QKV GEMM + RoPE ----------------
// Tile 128m x 256f; sel/head boundaries respected (256 | 512).
__global__ __launch_bounds__(256, 2) void qkv_mfma_kernel(
        const unsigned short* __restrict__ x_hi, const unsigned short* __restrict__ x_lo,
        const unsigned short* __restrict__ wq_bf,
        unsigned short* __restrict__ q_hi, unsigned short* __restrict__ q_lo,
        unsigned short* __restrict__ k_hi, unsigned short* __restrict__ k_lo,
        unsigned short* __restrict__ v_th) {
    __shared__ __align__(16) char lds[65536 + 4608];
    unsigned short* T = (unsigned short*)lds;             // 128 x TP transpose buffer
    float* t_cy = (float*)(lds + 65536);                  // [4][16]
    float* t_sy = t_cy + 64;
    float* t_cx = t_sy + 64;                              // [32][16]
    float* t_sx = t_cx + 512;

    const int m0 = blockIdx.x * 128;
    const int f0 = blockIdx.y * 256;
    const int t = threadIdx.x;
    const int w = t >> 6, lane = t & 63, l15 = lane & 15, quad = lane >> 4;
    const int mw = (w & 1) * 64, nw = (w >> 1) * 128;
    const int sel = f0 >> 9;                // 0=q,1=k,2=v
    const int bt = m0 >> 10;
    const int n0 = m0 & 1023;

    if (sel != 2) {
        for (int idx = t; idx < 576; idx += 256) {
            if (idx < 64) {
                const int yi = idx >> 4, j = idx & 15;
                const float pos = -1.0f + (float)((n0 >> 5) + yi) * (2.0f / 31.0f);
                float sv, cv; sincosf(pos * freq_of(j), &sv, &cv);
                t_sy[idx] = sv; t_cy[idx] = cv;
            } else {
                const int k2 = idx - 64, xi = k2 >> 4, j = k2 & 15;
                const float pos = -1.0f + (float)xi * (2.0f / 31.0f);
                float sv, cv; sincosf(pos * freq_of(j), &sv, &cv);
                t_sx[k2] = sv; t_cx[k2] = cv;
            }
        }
    }

    f32x4 acc[4][8];
    #pragma unroll
    for (int mt = 0; mt < 4; mt++)
        #pragma unroll
        for (int nt = 0; nt < 8; nt++) acc[mt][nt] = (f32x4){0.f, 0.f, 0.f, 0.f};

    gemm_pipe<2>(x_hi, x_lo, wq_bf, lds, m0, f0, t, acc);

    // rope in place (q,k); q additionally scaled by QSCALE so attn uses exp2
    if (sel != 2) {
        const float post = (sel == 0) ? QSCALE : 1.0f;
        #pragma unroll
        for (int mt = 0; mt < 4; mt++)
            #pragma unroll
            for (int nt = 0; nt < 8; nt++)
                #pragma unroll
                for (int rr = 0; rr < 4; rr++) {
                    const int ml = mw + mt * 16 + quad * 4 + rr;
                    const int dd = (nw + nt * 16 + l15) & 63;
                    const int j0 = (dd & 31) >> 1;
                    float c, s;
                    if (dd < 32) { c = t_cy[(ml >> 5) * 16 + j0]; s = t_sy[(ml >> 5) * 16 + j0]; }
                    else         { c = t_cx[(ml & 31) * 16 + j0]; s = t_sx[(ml & 31) * 16 + j0]; }
                    const float v = acc[mt][nt][rr];
                    const float pv = __shfl_xor(v, 1);
                    acc[mt][nt][rr] = ((l15 & 1) ? (v * c + pv * s) : (v * c - pv * s)) * post;
                }
    }

    // stores: q/k 2 passes (hi, lo) x 2 f-halves; v 1 pass (RTN) x 2 f-halves
    const int npass = (sel == 2) ? 1 : 2;
    for (int pass = 0; pass < npass; pass++) {
        for (int h = 0; h < 2; h++) {
            if ((nw >> 7) == h) {
                if (sel == 2) {
                    #pragma unroll
                    for (int mt = 0; mt < 4; mt++)
                        #pragma unroll
                        for (int nt = 0; nt < 8; nt++) {
                            const int fl = nt * 16 + l15;
                            const int mlb = mw + mt * 16 + quad * 4;
                            ushort4 pk = make_ushort4(
                                bf16_rtn(acc[mt][nt][0]), bf16_rtn(acc[mt][nt][1]),
                                bf16_rtn(acc[mt][nt][2]), bf16_rtn(acc[mt][nt][3]));
                            *(ushort4*)&T[fl * TP + mlb] = pk;
                        }
                } else {
                    #pragma unroll
                    for (int mt = 0; mt < 4; mt++)
                        #pragma unroll
                        for (int nt = 0; nt < 8; nt++)
                            #pragma unroll
                            for (int rr = 0; rr < 4; rr++) {
                                const int ml = mw + mt * 16 + quad * 4 + rr;
                                const int fl = nt * 16 + l15;
                                const float v = acc[mt][nt][rr];
                                const unsigned short hv = bf16_hi(v);
                                T[ml * TP + fl] = (pass == 0)
                                    ? hv : bf16_hi(v - bf16_tofloat(hv));
                            }
                }
            }
            __syncthreads();
            if (sel == 2) {
                #pragma unroll
                for (int p = 0; p < 8; p++) {
                    const int idx = p * 256 + t;
                    const int lrf = idx >> 4, g8 = (idx & 15) * 8;
                    const int fg = f0 + h * 128 + lrf;
                    const int head = (fg >> 6) & 7;
                    *(uint4*)(v_th + ((size_t)(bt * NH + head) * HD + (fg & 63)) * NSEQ
                              + n0 + g8) = *(const uint4*)&T[lrf * TP + g8];
                }
            } else {
                unsigned short* dst = (sel == 0) ? ((pass == 0) ? q_hi : q_lo)
                                                 : ((pass == 0) ? k_hi : k_lo);
                #pragma unroll
                for (int p = 0; p < 8; p++) {
                    const int idx = p * 256 + t;
                    const int lr = idx >> 4, g8 = (idx & 15) * 8;
                    const int fg = f0 + h * 128 + g8;
                    const int head = (fg >> 6) & 7;
                    *(uint4*)(dst + ((size_t)(bt * NH + head) * NSEQ + n0 + lr) * HD
                              + (fg & 63)) = *(const uint4*)&T[lr * TP + g8];
                }
            }
            __syncthreads();
        }
    }
}

// ---------------- Kernel 2: flash attention, no-max exp2 softmax ----------------
__global__ __launch_bounds__(256, 3) void attn_kernel(
        const unsigned short* __restrict__ q_hi, const unsigned short* __restrict__ q_lo,
        const unsigned short* __restrict__ k_hi, const unsigned short* __restrict__ k_lo,
        const unsigned short* __restrict__ v_th,
        unsigned short* __restrict__ o_bf) {
    __shared__ unsigned short Ks[128 * KVP];  // rows 0..63: K_hi, 64..127: K_lo
    __shared__ unsigned short Vsh[64 * KVP];  // V^T hi
    __shared__ unsigned short Ps[128 * 64];   // P, xor-swizzled cols, wave-private rows

    const int qt = blockIdx.x;     // 0..7
    const int bh = blockIdx.y;     // 0..127
    const int t = threadIdx.x;
    const int w = t >> 6;
    const int lane = t & 63;
    const int l15 = lane & 15;
    const int quad = lane >> 4;

    const size_t bh_nd = (size_t)bh * NSEQ * HD;
    const size_t bh_dn = (size_t)bh * HD * NSEQ;

    bf16x8 qfh[2][2], qfl[2][2];
    #pragma unroll
    for (int mf = 0; mf < 2; mf++) {
        const size_t rbase = bh_nd + (size_t)(qt * 128 + w * 32 + mf * 16 + l15) * HD;
        #pragma unroll
        for (int ks = 0; ks < 2; ks++) {
            qfh[mf][ks] = *(const bf16x8*)(q_hi + rbase + ks * 32 + quad * 8);
            qfl[mf][ks] = *(const bf16x8*)(q_lo + rbase + ks * 32 + quad * 8);
        }
    }

    const bf16x8 ones = {(short)0x3F80, (short)0x3F80, (short)0x3F80, (short)0x3F80,
                         (short)0x3F80, (short)0x3F80, (short)0x3F80, (short)0x3F80};

    f32x4 o_acc[2][4], l_acc[2];
    #pragma unroll
    for (int mf = 0; mf < 2; mf++) {
        l_acc[mf] = (f32x4){0.f, 0.f, 0.f, 0.f};
        #pragma unroll
        for (int dt = 0; dt < 4; dt++) o_acc[mf][dt] = (f32x4){0.f, 0.f, 0.f, 0.f};
    }

    for (int kt = 0; kt < 16; kt++) {
        __syncthreads();
        #pragma unroll
        for (int p = 0; p < 2; p++) {
            const int cc = t + p * 256;
            const int r = cc >> 3, off8 = (cc & 7) * 8;
            const size_t gk = bh_nd + (size_t)(kt * 64 + r) * HD + off8;
            *(uint4*)&Ks[r * KVP + off8]        = *(const uint4*)(k_hi + gk);
            *(uint4*)&Ks[(64 + r) * KVP + off8] = *(const uint4*)(k_lo + gk);
            const size_t gv = bh_dn + (size_t)r * NSEQ + kt * 64 + off8;
            *(uint4*)&Vsh[r * KVP + off8]       = *(const uint4*)(v_th + gv);
        }
        __syncthreads();

        // ---- S = Q K^T (hh+hl+lh), p = exp2(s), store P (bf16 RTN, swizzled) ----
        #pragma unroll
        for (int nt = 0; nt < 4; nt++) {
            bf16x8 kh[2], kl[2];
            #pragma unroll
            for (int ks = 0; ks < 2; ks++) {
                const int off = (nt * 16 + l15) * KVP + ks * 32 + quad * 8;
                kh[ks] = *(const bf16x8*)&Ks[off];
                kl[ks] = *(const bf16x8*)&Ks[64 * KVP + off];
            }
            #pragma unroll
            for (int mf = 0; mf < 2; mf++) {
                f32x4 s = (f32x4){0.f, 0.f, 0.f, 0.f};
                #pragma unroll
                for (int ks = 0; ks < 2; ks++) {
                    s = MFMA16(qfh[mf][ks], kh[ks], s);
                    s = MFMA16(qfh[mf][ks], kl[ks], s);
                    s = MFMA16(qfl[mf][ks], kh[ks], s);
                }
                const int prow_b = w * 32 + mf * 16 + quad * 4;
                const int col = nt * 16 + l15;
                #pragma unroll
                for (int r = 0; r < 4; r++) {
                    const int prow = prow_b + r;
                    const float pv = exp2f(s[r]);
                    Ps[prow * 64 + ((((col >> 3) ^ (prow & 7)) << 3) | (col & 7))] =
                        bf16_rtn(pv);
                }
            }
        }

        // ---- O += P V, l += P 1 (P wave-private: no barrier needed) ----
        bf16x8 pf[2][2];
        #pragma unroll
        for (int mf = 0; mf < 2; mf++) {
            const int prow = w * 32 + mf * 16 + l15;
            #pragma unroll
            for (int ks = 0; ks < 2; ks++)
                pf[mf][ks] = *(const bf16x8*)&Ps[prow * 64 +
                                (((ks * 4 + quad) ^ (prow & 7)) << 3)];
            l_acc[mf] = MFMA16(pf[mf][0], ones, l_acc[mf]);
            l_acc[mf] = MFMA16(pf[mf][1], ones, l_acc[mf]);
        }
        #pragma unroll
        for (int dt = 0; dt < 4; dt++) {
            bf16x8 vh[2];
            #pragma unroll
            for (int ks = 0; ks < 2; ks++)
                vh[ks] = *(const bf16x8*)&Vsh[(dt * 16 + l15) * KVP + ks * 32 + quad * 8];
            #pragma unroll
            for (int mf = 0; mf < 2; mf++) {
                o_acc[mf][dt] = MFMA16(pf[mf][0], vh[0], o_acc[mf][dt]);
                o_acc[mf][dt] = MFMA16(pf[mf][1], vh[1], o_acc[mf][dt]);
            }
        }
    }

    // ---- epilogue: normalize by l, single bf16 RTN plane for proj ----
    const int btq = bh >> 3, head = bh & 7;
    #pragma unroll
    for (int mf = 0; mf < 2; mf++)
        #pragma unroll
        for (int r = 0; r < 4; r++) {
            const float inv = 1.0f / l_acc[mf][r];
            const int row = qt * 128 + w * 32 + mf * 16 + quad * 4 + r;
            #pragma unroll
            for (int dt = 0; dt < 4; dt++) {
                const size_t off =
                    ((size_t)(btq * NSEQ + row)) * DMODEL + head * HD + dt * 16 + l15;
                o_bf[off] = bf16_rtn(o_acc[mf][dt][r] * inv);
            }
        }
}

// ---------------- Kernel 3: output projection (single-plane bf16) ----------------
__global__ __launch_bounds__(256, 2) void proj_mfma_kernel(
        const unsigned short* __restrict__ o_bf,
        const unsigned short* __restrict__ wo_bf,
        const float* __restrict__ b_out, float* __restrict__ out) {
    __shared__ __align__(16) char lds[49152];

    const int m0 = blockIdx.x * 128;
    const int f0 = blockIdx.y * 256;
    const int t = threadIdx.x;
    const int w = t >> 6, lane = t & 63, l15 = lane & 15, quad = lane >> 4;
    const int mw = (w & 1) * 64, nw = (w >> 1) * 128;

    f32x4 acc[4][8];
    #pragma unroll
    for (int mt = 0; mt < 4; mt++)
        #pragma unroll
        for (int nt = 0; nt < 8; nt++) acc[mt][nt] = (f32x4){0.f, 0.f, 0.f, 0.f};

    gemm_pipe<1>(o_bf, o_bf, wo_bf, lds, m0, f0, t, acc);

    float bias_v[8];
    #pragma unroll
    for (int nt = 0; nt < 8; nt++) bias_v[nt] = b_out[f0 + nw + nt * 16 + l15];
    #pragma unroll
    for (int mt = 0; mt < 4; mt++)
        #pragma unroll
        for (int nt = 0; nt < 8; nt++)
            #pragma unroll
            for (int rr = 0; rr < 4; rr++) {
                const int m = m0 + mw + mt * 16 + quad * 4 + rr;
                out[(size_t)m * DMODEL + f0 + nw + nt * 16 + l15] =
                    acc[mt][nt][rr] + bias_v[nt];
            }
}

extern "C" void kernel_launch(void* const* d_in, const int* in_sizes, int n_in,
                              void* d_out, int out_size, void* d_ws, size_t ws_size,
                              hipStream_t stream) {
    const float* x  = (const float*)d_in[0];
    const float* wq = (const float*)d_in[1];
    const float* wo = (const float*)d_in[2];
    const float* bo = (const float*)d_in[3];
    float* out = (float*)d_out;

    const size_t per = (size_t)BH * NSEQ * HD;   // 8,388,608 elements
    unsigned short* x_hi = (unsigned short*)d_ws;   // reused as o_bf after qkv
    unsigned short* x_lo = x_hi + per;
    unsigned short* q_hi = x_lo + per;
    unsigned short* q_lo = q_hi + per;
    unsigned short* k_hi = q_lo + per;
    unsigned short* k_lo = k_hi + per;
    unsigned short* v_th = k_lo + per;
    unsigned short* wq_bf = v_th + per;              // 786,432 els
    unsigned short* wo_bf = wq_bf + (size_t)F3 * DMODEL;  // 262,144 els (~120 MiB total)
    unsigned short* o_bf = x_hi;   // x dead after qkv

    split_kernel<<<dim3((int)(per / 1024)), 256, 0, stream>>>(x, x_hi, x_lo);
    cvt_kernel<<<dim3(F3 * DMODEL / 1024), 256, 0, stream>>>(wq, wq_bf);
    cvt_kernel<<<dim3(DMODEL * DMODEL / 1024), 256, 0, stream>>>(wo, wo_bf);
    qkv_mfma_kernel<<<dim3(NTOK / 128, F3 / 256), 256, 0, stream>>>(
        x_hi, x_lo, wq_bf, q_hi, q_lo, k_hi, k_lo, v_th);
    attn_kernel<<<dim3(8, BH), 256, 0, stream>>>(
        q_hi, q_lo, k_hi, k_lo, v_th, o_bf);
    proj_mfma_kernel<<<dim3(NTOK / 128, DMODEL / 256), 256, 0, stream>>>(
        o_bf, wo_bf, bo, out);
}

// Round 7
// 321.434 us; speedup vs baseline: 1.2794x; 1.2794x over previous
//
#include <hip/hip_runtime.h>
#include <math.h>

#define NH 8
#define HD 64
#define NSEQ 1024
#define DMODEL 512
#define F3 1536
#define NTOK 16384
#define BH 128    // (B*T)*NH = 16*8
#define KVP 72    // attn K/V LDS pitch (bf16)
#define TP 136    // qkv epilogue transpose pitch (bf16)
#define QSCALE 0.1803368867f  // 0.125 * log2(e), folded into q; p = exp2(s')

typedef __attribute__((ext_vector_type(8))) short bf16x8;
typedef __attribute__((ext_vector_type(4))) float f32x4;
#define MFMA16(a, b, c) __builtin_amdgcn_mfma_f32_16x16x32_bf16(a, b, c, 0, 0, 0)

__device__ __forceinline__ float freq_of(int j) {
    return 3.14159265358979323846f * (1.0f + (float)j * (127.0f / 15.0f));
}
__device__ __forceinline__ unsigned short bf16_hi(float x) {
    unsigned u = __builtin_bit_cast(unsigned, x);
    return (unsigned short)(u >> 16);   // truncation split; residual goes to lo
}
__device__ __forceinline__ unsigned short bf16_rtn(float x) {
    unsigned u = __builtin_bit_cast(unsigned, x);
    return (unsigned short)((u + 0x7FFF + ((u >> 16) & 1)) >> 16);  // round-nearest-even
}
__device__ __forceinline__ float bf16_tofloat(unsigned short h) {
    unsigned u = ((unsigned)h) << 16;
    return __builtin_bit_cast(float, u);
}
// 2-bit LDS swizzle key for row r (permutes 16-B col-groups within a 64-B row)
__device__ __forceinline__ int swz(int r) { return (r & 3) ^ ((r >> 2) & 3); }

// ---------------- Kernel 0a: split fp32 -> bf16 hi/lo (trunc) ----------------
__global__ __launch_bounds__(256) void split_kernel(
        const float* __restrict__ src, unsigned short* __restrict__ hi,
        unsigned short* __restrict__ lo) {
    const int i = blockIdx.x * 256 + threadIdx.x;
    const float4 v = ((const float4*)src)[i];
    ushort4 h, l;
    h.x = bf16_hi(v.x); l.x = bf16_hi(v.x - bf16_tofloat(h.x));
    h.y = bf16_hi(v.y); l.y = bf16_hi(v.y - bf16_tofloat(h.y));
    h.z = bf16_hi(v.z); l.z = bf16_hi(v.z - bf16_tofloat(h.z));
    h.w = bf16_hi(v.w); l.w = bf16_hi(v.w - bf16_tofloat(h.w));
    ((ushort4*)hi)[i] = h;
    ((ushort4*)lo)[i] = l;
}
// ---------------- Kernel 0b: fp32 -> bf16 RTN single plane ----------------
__global__ __launch_bounds__(256) void cvt_kernel(
        const float* __restrict__ src, unsigned short* __restrict__ dst) {
    const int i = blockIdx.x * 256 + threadIdx.x;
    const float4 v = ((const float4*)src)[i];
    ((ushort4*)dst)[i] = make_ushort4(bf16_rtn(v.x), bf16_rtn(v.y),
                                      bf16_rtn(v.z), bf16_rtn(v.w));
}

// ---- register-staged pipelined GEMM core: 128x128 tile, BK=32, 4 waves ----
// PLANES=3: {A_hi, A_lo, B}; PLANES=2: {A, B}. Global->VGPR loads for kt+1 are
// issued BEFORE compute(kt); ds_write after compute; one barrier/iter. The
// vmcnt wait thus lands after a full MFMA phase (latency hidden), unlike
// global_load_lds whose completion chains into the barrier's vmcnt(0) drain.
// XOR-swizzled LDS layout: frag ds_read_b128 is 2-way banked (free, m136).
template<int PLANES>
__device__ __forceinline__ void gemm_reg_pipe(
        const unsigned short* __restrict__ a_hi, const unsigned short* __restrict__ a_lo,
        const unsigned short* __restrict__ b_bf,
        char* lds, int m0, int f0, int t, f32x4 acc[4][4]) {
    const int w = t >> 6, lane = t & 63, l15 = lane & 15, quad = lane >> 4;
    const int mw = (w & 1) * 64, nw = (w >> 1) * 64;
    const int STAGE = PLANES * 4096;      // elements per stage
    const int r = t >> 1;                 // 0..127: row this thread stages
    const int g0 = (t & 1) * 2;           // first of two 16-B col-groups

    uint4 regs[PLANES][2];
    auto load_regs = [&](int kt) {
        const int k0 = kt * 32;
        #pragma unroll
        for (int p = 0; p < PLANES; p++) {
            const unsigned short* src =
                (p == 0) ? a_hi : ((p == PLANES - 1) ? b_bf : a_lo);
            const int row0 = (p == PLANES - 1) ? f0 : m0;
            const unsigned short* g = src + (size_t)(row0 + r) * DMODEL + k0 + g0 * 8;
            regs[p][0] = *(const uint4*)g;
            regs[p][1] = *(const uint4*)(g + 8);
        }
    };
    auto store_lds = [&](int stage) {
        unsigned short* S = (unsigned short*)lds + stage * STAGE;
        const int s0 = ((g0 ^ swz(r))) * 8;
        const int s1 = (((g0 + 1) ^ swz(r))) * 8;
        #pragma unroll
        for (int p = 0; p < PLANES; p++) {
            unsigned short* Sp = S + p * 4096 + r * 32;
            *(uint4*)&Sp[s0] = regs[p][0];
            *(uint4*)&Sp[s1] = regs[p][1];
        }
    };

    load_regs(0);
    store_lds(0);
    for (int kt = 0; kt < 16; kt++) {
        __syncthreads();                  // stage (kt&1) visible to all waves
        if (kt < 15) load_regs(kt + 1);   // issue next tile's global loads NOW
        const unsigned short* S = (const unsigned short*)lds + (kt & 1) * STAGE;
        bf16x8 ah[4], al[4], bb[4];
        #pragma unroll
        for (int mt = 0; mt < 4; mt++) {
            const int rr = mw + mt * 16 + l15;
            const int off = rr * 32 + (quad ^ swz(rr)) * 8;
            ah[mt] = *(const bf16x8*)&S[off];
            if (PLANES == 3) al[mt] = *(const bf16x8*)&S[4096 + off];
        }
        #pragma unroll
        for (int nt = 0; nt < 4; nt++) {
            const int rr = nw + nt * 16 + l15;
            bb[nt] = *(const bf16x8*)&S[(PLANES - 1) * 4096 + rr * 32
                                        + (quad ^ swz(rr)) * 8];
        }
        #pragma unroll
        for (int mt = 0; mt < 4; mt++)
            #pragma unroll
            for (int nt = 0; nt < 4; nt++) {
                acc[mt][nt] = MFMA16(ah[mt], bb[nt], acc[mt][nt]);
                if (PLANES == 3) acc[mt][nt] = MFMA16(al[mt], bb[nt], acc[mt][nt]);
            }
        if (kt < 15) store_lds((kt + 1) & 1);  // vmcnt wait lands here, post-MFMA
    }
    __syncthreads();                      // LDS free for epilogue reuse
}

// ---------------- Kernel 1: QKV GEMM + RoPE (128x128 tile) ----------------
__global__ __launch_bounds__(256, 3) void qkv_mfma_kernel(
        const unsigned short* __restrict__ x_hi, const unsigned short* __restrict__ x_lo,
        const unsigned short* __restrict__ wq_bf,
        unsigned short* __restrict__ q_hi, unsigned short* __restrict__ q_lo,
        unsigned short* __restrict__ k_hi, unsigned short* __restrict__ k_lo,
        unsigned short* __restrict__ v_th) {
    __shared__ __align__(16) char lds[49152 + 4608];   // 2x24KB stages (+T alias) + tables
    unsigned short* T = (unsigned short*)lds;          // 128 x TP transpose buffer
    float* t_cy = (float*)(lds + 49152);               // [4][16]
    float* t_sy = t_cy + 64;
    float* t_cx = t_sy + 64;                           // [32][16]
    float* t_sx = t_cx + 512;

    const int m0 = blockIdx.x * 128;
    const int f0 = blockIdx.y * 128;
    const int t = threadIdx.x;
    const int w = t >> 6, lane = t & 63, l15 = lane & 15, quad = lane >> 4;
    const int mw = (w & 1) * 64, nw = (w >> 1) * 64;
    const int sel = f0 >> 9;                // 0=q,1=k,2=v
    const int bt = m0 >> 10;
    const int n0 = m0 & 1023;

    if (sel != 2) {
        for (int idx = t; idx < 576; idx += 256) {
            if (idx < 64) {
                const int yi = idx >> 4, j = idx & 15;
                const float pos = -1.0f + (float)((n0 >> 5) + yi) * (2.0f / 31.0f);
                float sv, cv; sincosf(pos * freq_of(j), &sv, &cv);
                t_sy[idx] = sv; t_cy[idx] = cv;
            } else {
                const int k2 = idx - 64, xi = k2 >> 4, j = k2 & 15;
                const float pos = -1.0f + (float)xi * (2.0f / 31.0f);
                float sv, cv; sincosf(pos * freq_of(j), &sv, &cv);
                t_sx[k2] = sv; t_cx[k2] = cv;
            }
        }
    }
    __syncthreads();   // tables ready before stage region reused... (tables separate; safe)

    f32x4 acc[4][4];
    #pragma unroll
    for (int mt = 0; mt < 4; mt++)
        #pragma unroll
        for (int nt = 0; nt < 4; nt++) acc[mt][nt] = (f32x4){0.f, 0.f, 0.f, 0.f};

    gemm_reg_pipe<3>(x_hi, x_lo, wq_bf, lds, m0, f0, t, acc);

    // rope in place (q,k); q additionally scaled by QSCALE so attn uses exp2
    if (sel != 2) {
        const float post = (sel == 0) ? QSCALE : 1.0f;
        #pragma unroll
        for (int mt = 0; mt < 4; mt++)
            #pragma unroll
            for (int nt = 0; nt < 4; nt++)
                #pragma unroll
                for (int rr = 0; rr < 4; rr++) {
                    const int ml = mw + mt * 16 + quad * 4 + rr;
                    const int dd = (nw + nt * 16 + l15) & 63;
                    const int j0 = (dd & 31) >> 1;
                    float c, s;
                    if (dd < 32) { c = t_cy[(ml >> 5) * 16 + j0]; s = t_sy[(ml >> 5) * 16 + j0]; }
                    else         { c = t_cx[(ml & 31) * 16 + j0]; s = t_sx[(ml & 31) * 16 + j0]; }
                    const float v = acc[mt][nt][rr];
                    const float pv = __shfl_xor(v, 1);
                    acc[mt][nt][rr] = ((l15 & 1) ? (v * c + pv * s) : (v * c - pv * s)) * post;
                }
    }

    // stores through T: q/k two passes (hi, lo); v one pass (RTN), transposed
    const int npass = (sel == 2) ? 1 : 2;
    for (int pass = 0; pass < npass; pass++) {
        if (sel == 2) {
            #pragma unroll
            for (int mt = 0; mt < 4; mt++)
                #pragma unroll
                for (int nt = 0; nt < 4; nt++) {
                    const int fl = nw + nt * 16 + l15;
                    const int mlb = mw + mt * 16 + quad * 4;
                    ushort4 pk = make_ushort4(
                        bf16_rtn(acc[mt][nt][0]), bf16_rtn(acc[mt][nt][1]),
                        bf16_rtn(acc[mt][nt][2]), bf16_rtn(acc[mt][nt][3]));
                    *(ushort4*)&T[fl * TP + mlb] = pk;
                }
        } else {
            #pragma unroll
            for (int mt = 0; mt < 4; mt++)
                #pragma unroll
                for (int nt = 0; nt < 4; nt++)
                    #pragma unroll
                    for (int rr = 0; rr < 4; rr++) {
                        const int ml = mw + mt * 16 + quad * 4 + rr;
                        const int fl = nw + nt * 16 + l15;
                        const float v = acc[mt][nt][rr];
                        const unsigned short hv = bf16_hi(v);
                        T[ml * TP + fl] = (pass == 0) ? hv
                                                      : bf16_hi(v - bf16_tofloat(hv));
                    }
        }
        __syncthreads();
        if (sel == 2) {
            #pragma unroll
            for (int p = 0; p < 8; p++) {
                const int idx = p * 256 + t;
                const int fl = idx >> 4, g8 = (idx & 15) * 8;
                const int head = ((f0 + fl) >> 6) & 7;
                *(uint4*)(v_th + ((size_t)(bt * NH + head) * HD + ((f0 + fl) & 63)) * NSEQ
                          + n0 + g8) = *(const uint4*)&T[fl * TP + g8];
            }
        } else {
            unsigned short* dst = (sel == 0) ? ((pass == 0) ? q_hi : q_lo)
                                             : ((pass == 0) ? k_hi : k_lo);
            #pragma unroll
            for (int p = 0; p < 8; p++) {
                const int idx = p * 256 + t;
                const int ml = idx >> 4, g8 = (idx & 15) * 8;
                const int head = ((f0 + g8) >> 6) & 7;
                *(uint4*)(dst + ((size_t)(bt * NH + head) * NSEQ + n0 + ml) * HD
                          + ((f0 + g8) & 63)) = *(const uint4*)&T[ml * TP + g8];
            }
        }
        __syncthreads();
    }
}

// ---------------- Kernel 2: flash attention, no-max exp2 softmax ----------------
__global__ __launch_bounds__(256, 3) void attn_kernel(
        const unsigned short* __restrict__ q_hi, const unsigned short* __restrict__ q_lo,
        const unsigned short* __restrict__ k_hi, const unsigned short* __restrict__ k_lo,
        const unsigned short* __restrict__ v_th,
        unsigned short* __restrict__ o_bf) {
    __shared__ unsigned short Ks[128 * KVP];  // rows 0..63: K_hi, 64..127: K_lo
    __shared__ unsigned short Vsh[64 * KVP];  // V^T hi
    __shared__ unsigned short Ps[128 * 64];   // P, xor-swizzled cols, wave-private rows

    const int qt = blockIdx.x;     // 0..7
    const int bh = blockIdx.y;     // 0..127
    const int t = threadIdx.x;
    const int w = t >> 6;
    const int lane = t & 63;
    const int l15 = lane & 15;
    const int quad = lane >> 4;

    const size_t bh_nd = (size_t)bh * NSEQ * HD;
    const size_t bh_dn = (size_t)bh * HD * NSEQ;

    bf16x8 qfh[2][2], qfl[2][2];
    #pragma unroll
    for (int mf = 0; mf < 2; mf++) {
        const size_t rbase = bh_nd + (size_t)(qt * 128 + w * 32 + mf * 16 + l15) * HD;
        #pragma unroll
        for (int ks = 0; ks < 2; ks++) {
            qfh[mf][ks] = *(const bf16x8*)(q_hi + rbase + ks * 32 + quad * 8);
            qfl[mf][ks] = *(const bf16x8*)(q_lo + rbase + ks * 32 + quad * 8);
        }
    }

    const bf16x8 ones = {(short)0x3F80, (short)0x3F80, (short)0x3F80, (short)0x3F80,
                         (short)0x3F80, (short)0x3F80, (short)0x3F80, (short)0x3F80};

    f32x4 o_acc[2][4], l_acc[2];
    #pragma unroll
    for (int mf = 0; mf < 2; mf++) {
        l_acc[mf] = (f32x4){0.f, 0.f, 0.f, 0.f};
        #pragma unroll
        for (int dt = 0; dt < 4; dt++) o_acc[mf][dt] = (f32x4){0.f, 0.f, 0.f, 0.f};
    }

    for (int kt = 0; kt < 16; kt++) {
        __syncthreads();
        #pragma unroll
        for (int p = 0; p < 2; p++) {
            const int cc = t + p * 256;
            const int r = cc >> 3, off8 = (cc & 7) * 8;
            const size_t gk = bh_nd + (size_t)(kt * 64 + r) * HD + off8;
            *(uint4*)&Ks[r * KVP + off8]        = *(const uint4*)(k_hi + gk);
            *(uint4*)&Ks[(64 + r) * KVP + off8] = *(const uint4*)(k_lo + gk);
            const size_t gv = bh_dn + (size_t)r * NSEQ + kt * 64 + off8;
            *(uint4*)&Vsh[r * KVP + off8]       = *(const uint4*)(v_th + gv);
        }
        __syncthreads();

        // ---- S = Q K^T (hh+hl+lh), p = exp2(s), store P (bf16 RTN, swizzled) ----
        #pragma unroll
        for (int nt = 0; nt < 4; nt++) {
            bf16x8 kh[2], kl[2];
            #pragma unroll
            for (int ks = 0; ks < 2; ks++) {
                const int off = (nt * 16 + l15) * KVP + ks * 32 + quad * 8;
                kh[ks] = *(const bf16x8*)&Ks[off];
                kl[ks] = *(const bf16x8*)&Ks[64 * KVP + off];
            }
            #pragma unroll
            for (int mf = 0; mf < 2; mf++) {
                f32x4 s = (f32x4){0.f, 0.f, 0.f, 0.f};
                #pragma unroll
                for (int ks = 0; ks < 2; ks++) {
                    s = MFMA16(qfh[mf][ks], kh[ks], s);
                    s = MFMA16(qfh[mf][ks], kl[ks], s);
                    s = MFMA16(qfl[mf][ks], kh[ks], s);
                }
                const int prow_b = w * 32 + mf * 16 + quad * 4;
                const int col = nt * 16 + l15;
                #pragma unroll
                for (int r = 0; r < 4; r++) {
                    const int prow = prow_b + r;
                    const float pv = exp2f(s[r]);
                    Ps[prow * 64 + ((((col >> 3) ^ (prow & 7)) << 3) | (col & 7))] =
                        bf16_rtn(pv);
                }
            }
        }

        // ---- O += P V, l += P 1 (P wave-private: no barrier needed) ----
        bf16x8 pf[2][2];
        #pragma unroll
        for (int mf = 0; mf < 2; mf++) {
            const int prow = w * 32 + mf * 16 + l15;
            #pragma unroll
            for (int ks = 0; ks < 2; ks++)
                pf[mf][ks] = *(const bf16x8*)&Ps[prow * 64 +
                                (((ks * 4 + quad) ^ (prow & 7)) << 3)];
            l_acc[mf] = MFMA16(pf[mf][0], ones, l_acc[mf]);
            l_acc[mf] = MFMA16(pf[mf][1], ones, l_acc[mf]);
        }
        #pragma unroll
        for (int dt = 0; dt < 4; dt++) {
            bf16x8 vh[2];
            #pragma unroll
            for (int ks = 0; ks < 2; ks++)
                vh[ks] = *(const bf16x8*)&Vsh[(dt * 16 + l15) * KVP + ks * 32 + quad * 8];
            #pragma unroll
            for (int mf = 0; mf < 2; mf++) {
                o_acc[mf][dt] = MFMA16(pf[mf][0], vh[0], o_acc[mf][dt]);
                o_acc[mf][dt] = MFMA16(pf[mf][1], vh[1], o_acc[mf][dt]);
            }
        }
    }

    // ---- epilogue: normalize by l, single bf16 RTN plane for proj ----
    const int btq = bh >> 3, head = bh & 7;
    #pragma unroll
    for (int mf = 0; mf < 2; mf++)
        #pragma unroll
        for (int r = 0; r < 4; r++) {
            const float inv = 1.0f / l_acc[mf][r];
            const int row = qt * 128 + w * 32 + mf * 16 + quad * 4 + r;
            #pragma unroll
            for (int dt = 0; dt < 4; dt++) {
                const size_t off =
                    ((size_t)(btq * NSEQ + row)) * DMODEL + head * HD + dt * 16 + l15;
                o_bf[off] = bf16_rtn(o_acc[mf][dt][r] * inv);
            }
        }
}

// ---------------- Kernel 3: output projection (2-plane, pipelined) ----------------
__global__ __launch_bounds__(256, 3) void proj_mfma_kernel(
        const unsigned short* __restrict__ o_bf,
        const unsigned short* __restrict__ wo_bf,
        const float* __restrict__ b_out, float* __restrict__ out) {
    __shared__ __align__(16) char lds[32768];   // 2 x 16KB stages

    const int m0 = blockIdx.x * 128;
    const int f0 = blockIdx.y * 128;
    const int t = threadIdx.x;
    const int w = t >> 6, lane = t & 63, l15 = lane & 15, quad = lane >> 4;
    const int mw = (w & 1) * 64, nw = (w >> 1) * 64;

    f32x4 acc[4][4];
    #pragma unroll
    for (int mt = 0; mt < 4; mt++)
        #pragma unroll
        for (int nt = 0; nt < 4; nt++) acc[mt][nt] = (f32x4){0.f, 0.f, 0.f, 0.f};

    gemm_reg_pipe<2>(o_bf, o_bf, wo_bf, lds, m0, f0, t, acc);

    float bias_v[4];
    #pragma unroll
    for (int nt = 0; nt < 4; nt++) bias_v[nt] = b_out[f0 + nw + nt * 16 + l15];
    #pragma unroll
    for (int mt = 0; mt < 4; mt++)
        #pragma unroll
        for (int nt = 0; nt < 4; nt++)
            #pragma unroll
            for (int rr = 0; rr < 4; rr++) {
                const int m = m0 + mw + mt * 16 + quad * 4 + rr;
                out[(size_t)m * DMODEL + f0 + nw + nt * 16 + l15] =
                    acc[mt][nt][rr] + bias_v[nt];
            }
}

extern "C" void kernel_launch(void* const* d_in, const int* in_sizes, int n_in,
                              void* d_out, int out_size, void* d_ws, size_t ws_size,
                              hipStream_t stream) {
    const float* x  = (const float*)d_in[0];
    const float* wq = (const float*)d_in[1];
    const float* wo = (const float*)d_in[2];
    const float* bo = (const float*)d_in[3];
    float* out = (float*)d_out;

    const size_t per = (size_t)BH * NSEQ * HD;   // 8,388,608 elements
    unsigned short* x_hi = (unsigned short*)d_ws;   // reused as o_bf after qkv
    unsigned short* x_lo = x_hi + per;
    unsigned short* q_hi = x_lo + per;
    unsigned short* q_lo = q_hi + per;
    unsigned short* k_hi = q_lo + per;
    unsigned short* k_lo = k_hi + per;
    unsigned short* v_th = k_lo + per;
    unsigned short* wq_bf = v_th + per;                   // 786,432 els
    unsigned short* wo_bf = wq_bf + (size_t)F3 * DMODEL;  // 262,144 els
    unsigned short* o_bf = x_hi;   // x dead after qkv

    split_kernel<<<dim3((int)(per / 1024)), 256, 0, stream>>>(x, x_hi, x_lo);
    cvt_kernel<<<dim3(F3 * DMODEL / 1024), 256, 0, stream>>>(wq, wq_bf);
    cvt_kernel<<<dim3(DMODEL * DMODEL / 1024), 256, 0, stream>>>(wo, wo_bf);
    qkv_mfma_kernel<<<dim3(NTOK / 128, F3 / 128), 256, 0, stream>>>(
        x_hi, x_lo, wq_bf, q_hi, q_lo, k_hi, k_lo, v_th);
    attn_kernel<<<dim3(8, BH), 256, 0, stream>>>(
        q_hi, q_lo, k_hi, k_lo, v_th, o_bf);
    proj_mfma_kernel<<<dim3(NTOK / 128, DMODEL / 128), 256, 0, stream>>>(
        o_bf, wo_bf, bo, out);
}

// Round 8
// 273.862 us; speedup vs baseline: 1.5016x; 1.1737x over previous
//
#include <hip/hip_runtime.h>
#include <math.h>

#define NH 8
#define HD 64
#define NSEQ 1024
#define DMODEL 512
#define F3 1536
#define NTOK 16384
#define BH 128    // (B*T)*NH = 16*8
#define KVP 72    // attn K/V LDS pitch (bf16)
#define TP 136    // qkv epilogue transpose pitch (bf16)
#define QSCALE 0.1803368867f  // 0.125 * log2(e), folded into q; p = exp2(s')

typedef __attribute__((ext_vector_type(8))) short bf16x8;
typedef __attribute__((ext_vector_type(4))) float f32x4;
#define MFMA16(a, b, c) __builtin_amdgcn_mfma_f32_16x16x32_bf16(a, b, c, 0, 0, 0)

__device__ __forceinline__ float freq_of(int j) {
    return 3.14159265358979323846f * (1.0f + (float)j * (127.0f / 15.0f));
}
__device__ __forceinline__ unsigned short bf16_hi(float x) {
    unsigned u = __builtin_bit_cast(unsigned, x);
    return (unsigned short)(u >> 16);   // truncation split; residual goes to lo
}
__device__ __forceinline__ unsigned short bf16_rtn(float x) {
    unsigned u = __builtin_bit_cast(unsigned, x);
    return (unsigned short)((u + 0x7FFF + ((u >> 16) & 1)) >> 16);  // round-nearest-even
}
__device__ __forceinline__ float bf16_tofloat(unsigned short h) {
    unsigned u = ((unsigned)h) << 16;
    return __builtin_bit_cast(float, u);
}
// 2-bit LDS swizzle key for row r (permutes 16-B col-groups within a 64-B row)
__device__ __forceinline__ int swz(int r) { return (r & 3) ^ ((r >> 2) & 3); }

// ---------------- Kernel 0a: split fp32 -> bf16 hi/lo (trunc) ----------------
__global__ __launch_bounds__(256) void split_kernel(
        const float* __restrict__ src, unsigned short* __restrict__ hi,
        unsigned short* __restrict__ lo) {
    const int i = blockIdx.x * 256 + threadIdx.x;
    const float4 v = ((const float4*)src)[i];
    ushort4 h, l;
    h.x = bf16_hi(v.x); l.x = bf16_hi(v.x - bf16_tofloat(h.x));
    h.y = bf16_hi(v.y); l.y = bf16_hi(v.y - bf16_tofloat(h.y));
    h.z = bf16_hi(v.z); l.z = bf16_hi(v.z - bf16_tofloat(h.z));
    h.w = bf16_hi(v.w); l.w = bf16_hi(v.w - bf16_tofloat(h.w));
    ((ushort4*)hi)[i] = h;
    ((ushort4*)lo)[i] = l;
}
// ---------------- Kernel 0b: fp32 -> bf16 RTN single plane ----------------
__global__ __launch_bounds__(256) void cvt_kernel(
        const float* __restrict__ src, unsigned short* __restrict__ dst) {
    const int i = blockIdx.x * 256 + threadIdx.x;
    const float4 v = ((const float4*)src)[i];
    ((ushort4*)dst)[i] = make_ushort4(bf16_rtn(v.x), bf16_rtn(v.y),
                                      bf16_rtn(v.z), bf16_rtn(v.w));
}

// ---- register-staged pipelined GEMM core: 128x128 tile, BK=32, 4 waves ----
// PLANES=3: {A_hi, A_lo, B}; PLANES=2: {A, B}. Global->VGPR loads for kt+1
// issued BEFORE compute(kt); ds_write after; one barrier/iter.
template<int PLANES>
__device__ __forceinline__ void gemm_reg_pipe(
        const unsigned short* __restrict__ a_hi, const unsigned short* __restrict__ a_lo,
        const unsigned short* __restrict__ b_bf,
        char* lds, int m0, int f0, int t, f32x4 acc[4][4]) {
    const int w = t >> 6, lane = t & 63, l15 = lane & 15, quad = lane >> 4;
    const int mw = (w & 1) * 64, nw = (w >> 1) * 64;
    const int STAGE = PLANES * 4096;      // elements per stage
    const int r = t >> 1;                 // 0..127: row this thread stages
    const int g0 = (t & 1) * 2;           // first of two 16-B col-groups

    uint4 regs[PLANES][2];
    auto load_regs = [&](int kt) {
        const int k0 = kt * 32;
        #pragma unroll
        for (int p = 0; p < PLANES; p++) {
            const unsigned short* src =
                (p == 0) ? a_hi : ((p == PLANES - 1) ? b_bf : a_lo);
            const int row0 = (p == PLANES - 1) ? f0 : m0;
            const unsigned short* g = src + (size_t)(row0 + r) * DMODEL + k0 + g0 * 8;
            regs[p][0] = *(const uint4*)g;
            regs[p][1] = *(const uint4*)(g + 8);
        }
    };
    auto store_lds = [&](int stage) {
        unsigned short* S = (unsigned short*)lds + stage * STAGE;
        const int s0 = ((g0 ^ swz(r))) * 8;
        const int s1 = (((g0 + 1) ^ swz(r))) * 8;
        #pragma unroll
        for (int p = 0; p < PLANES; p++) {
            unsigned short* Sp = S + p * 4096 + r * 32;
            *(uint4*)&Sp[s0] = regs[p][0];
            *(uint4*)&Sp[s1] = regs[p][1];
        }
    };

    load_regs(0);
    store_lds(0);
    for (int kt = 0; kt < 16; kt++) {
        __syncthreads();                  // stage (kt&1) visible to all waves
        if (kt < 15) load_regs(kt + 1);   // issue next tile's global loads NOW
        const unsigned short* S = (const unsigned short*)lds + (kt & 1) * STAGE;
        bf16x8 ah[4], al[4], bb[4];
        #pragma unroll
        for (int mt = 0; mt < 4; mt++) {
            const int rr = mw + mt * 16 + l15;
            const int off = rr * 32 + (quad ^ swz(rr)) * 8;
            ah[mt] = *(const bf16x8*)&S[off];
            if (PLANES == 3) al[mt] = *(const bf16x8*)&S[4096 + off];
        }
        #pragma unroll
        for (int nt = 0; nt < 4; nt++) {
            const int rr = nw + nt * 16 + l15;
            bb[nt] = *(const bf16x8*)&S[(PLANES - 1) * 4096 + rr * 32
                                        + (quad ^ swz(rr)) * 8];
        }
        #pragma unroll
        for (int mt = 0; mt < 4; mt++)
            #pragma unroll
            for (int nt = 0; nt < 4; nt++) {
                acc[mt][nt] = MFMA16(ah[mt], bb[nt], acc[mt][nt]);
                if (PLANES == 3) acc[mt][nt] = MFMA16(al[mt], bb[nt], acc[mt][nt]);
            }
        if (kt < 15) store_lds((kt + 1) & 1);  // vmcnt wait lands here, post-MFMA
    }
    __syncthreads();                      // LDS free for epilogue reuse
}

// ---------------- Kernel 1: QKV GEMM + RoPE (128x128 tile) ----------------
// Outputs: q_bf (RTN, QSCALE folded), k_bf (RTN), v_th (RTN, transposed).
__global__ __launch_bounds__(256, 3) void qkv_mfma_kernel(
        const unsigned short* __restrict__ x_hi, const unsigned short* __restrict__ x_lo,
        const unsigned short* __restrict__ wq_bf,
        unsigned short* __restrict__ q_bf, unsigned short* __restrict__ k_bf,
        unsigned short* __restrict__ v_th) {
    __shared__ __align__(16) char lds[49152 + 4608];   // 2x24KB stages (+T alias) + tables
    unsigned short* T = (unsigned short*)lds;          // 128 x TP transpose buffer
    float* t_cy = (float*)(lds + 49152);               // [4][16]
    float* t_sy = t_cy + 64;
    float* t_cx = t_sy + 64;                           // [32][16]
    float* t_sx = t_cx + 512;

    const int m0 = blockIdx.x * 128;
    const int f0 = blockIdx.y * 128;
    const int t = threadIdx.x;
    const int w = t >> 6, lane = t & 63, l15 = lane & 15, quad = lane >> 4;
    const int mw = (w & 1) * 64, nw = (w >> 1) * 64;
    const int sel = f0 >> 9;                // 0=q,1=k,2=v
    const int bt = m0 >> 10;
    const int n0 = m0 & 1023;

    if (sel != 2) {
        for (int idx = t; idx < 576; idx += 256) {
            if (idx < 64) {
                const int yi = idx >> 4, j = idx & 15;
                const float pos = -1.0f + (float)((n0 >> 5) + yi) * (2.0f / 31.0f);
                float sv, cv; sincosf(pos * freq_of(j), &sv, &cv);
                t_sy[idx] = sv; t_cy[idx] = cv;
            } else {
                const int k2 = idx - 64, xi = k2 >> 4, j = k2 & 15;
                const float pos = -1.0f + (float)xi * (2.0f / 31.0f);
                float sv, cv; sincosf(pos * freq_of(j), &sv, &cv);
                t_sx[k2] = sv; t_cx[k2] = cv;
            }
        }
    }
    __syncthreads();

    f32x4 acc[4][4];
    #pragma unroll
    for (int mt = 0; mt < 4; mt++)
        #pragma unroll
        for (int nt = 0; nt < 4; nt++) acc[mt][nt] = (f32x4){0.f, 0.f, 0.f, 0.f};

    gemm_reg_pipe<3>(x_hi, x_lo, wq_bf, lds, m0, f0, t, acc);

    // rope in place (q,k); q additionally scaled by QSCALE so attn uses exp2
    if (sel != 2) {
        const float post = (sel == 0) ? QSCALE : 1.0f;
        #pragma unroll
        for (int mt = 0; mt < 4; mt++)
            #pragma unroll
            for (int nt = 0; nt < 4; nt++)
                #pragma unroll
                for (int rr = 0; rr < 4; rr++) {
                    const int ml = mw + mt * 16 + quad * 4 + rr;
                    const int dd = (nw + nt * 16 + l15) & 63;
                    const int j0 = (dd & 31) >> 1;
                    float c, s;
                    if (dd < 32) { c = t_cy[(ml >> 5) * 16 + j0]; s = t_sy[(ml >> 5) * 16 + j0]; }
                    else         { c = t_cx[(ml & 31) * 16 + j0]; s = t_sx[(ml & 31) * 16 + j0]; }
                    const float v = acc[mt][nt][rr];
                    const float pv = __shfl_xor(v, 1);
                    acc[mt][nt][rr] = ((l15 & 1) ? (v * c + pv * s) : (v * c - pv * s)) * post;
                }
    }

    // single RTN pass through T; v transposed, q/k row-major
    if (sel == 2) {
        #pragma unroll
        for (int mt = 0; mt < 4; mt++)
            #pragma unroll
            for (int nt = 0; nt < 4; nt++) {
                const int fl = nw + nt * 16 + l15;
                const int mlb = mw + mt * 16 + quad * 4;
                ushort4 pk = make_ushort4(
                    bf16_rtn(acc[mt][nt][0]), bf16_rtn(acc[mt][nt][1]),
                    bf16_rtn(acc[mt][nt][2]), bf16_rtn(acc[mt][nt][3]));
                *(ushort4*)&T[fl * TP + mlb] = pk;
            }
    } else {
        #pragma unroll
        for (int mt = 0; mt < 4; mt++)
            #pragma unroll
            for (int nt = 0; nt < 4; nt++)
                #pragma unroll
                for (int rr = 0; rr < 4; rr++) {
                    const int ml = mw + mt * 16 + quad * 4 + rr;
                    const int fl = nw + nt * 16 + l15;
                    T[ml * TP + fl] = bf16_rtn(acc[mt][nt][rr]);
                }
    }
    __syncthreads();
    if (sel == 2) {
        #pragma unroll
        for (int p = 0; p < 8; p++) {
            const int idx = p * 256 + t;
            const int fl = idx >> 4, g8 = (idx & 15) * 8;
            const int head = ((f0 + fl) >> 6) & 7;
            *(uint4*)(v_th + ((size_t)(bt * NH + head) * HD + ((f0 + fl) & 63)) * NSEQ
                      + n0 + g8) = *(const uint4*)&T[fl * TP + g8];
        }
    } else {
        unsigned short* dst = (sel == 0) ? q_bf : k_bf;
        #pragma unroll
        for (int p = 0; p < 8; p++) {
            const int idx = p * 256 + t;
            const int ml = idx >> 4, g8 = (idx & 15) * 8;
            const int head = ((f0 + g8) >> 6) & 7;
            *(uint4*)(dst + ((size_t)(bt * NH + head) * NSEQ + n0 + ml) * HD
                      + ((f0 + g8) & 63)) = *(const uint4*)&T[ml * TP + g8];
        }
    }
    __syncthreads();
}

// ---------------- Kernel 2: flash attention, single-plane q/k, reg-staged KV ----
// p = exp2(s) (QSCALE in q); row-sum via all-ones MFMA; P wave-private.
// K/V double-buffered through registers: load(kt+1) before compute(kt).
__global__ __launch_bounds__(256, 3) void attn_kernel(
        const unsigned short* __restrict__ q_bf, const unsigned short* __restrict__ k_bf,
        const unsigned short* __restrict__ v_th,
        unsigned short* __restrict__ o_bf) {
    __shared__ unsigned short Ks[2][64 * KVP];  // K tile, double-buffered
    __shared__ unsigned short Vs[2][64 * KVP];  // V^T tile, double-buffered
    __shared__ unsigned short Ps[128 * 64];     // P, xor-swizzled, wave-private rows

    const int qt = blockIdx.x;     // 0..7
    const int bh = blockIdx.y;     // 0..127
    const int t = threadIdx.x;
    const int w = t >> 6;
    const int lane = t & 63;
    const int l15 = lane & 15;
    const int quad = lane >> 4;

    const size_t bh_nd = (size_t)bh * NSEQ * HD;
    const size_t bh_dn = (size_t)bh * HD * NSEQ;

    // Q fragments from global (once per block)
    bf16x8 qf[2][2];
    #pragma unroll
    for (int mf = 0; mf < 2; mf++) {
        const size_t rbase = bh_nd + (size_t)(qt * 128 + w * 32 + mf * 16 + l15) * HD;
        #pragma unroll
        for (int ks = 0; ks < 2; ks++)
            qf[mf][ks] = *(const bf16x8*)(q_bf + rbase + ks * 32 + quad * 8);
    }

    uint4 kr[2], vr[2];
    auto load_kv = [&](int kt) {
        #pragma unroll
        for (int p = 0; p < 2; p++) {
            const int cc = t + p * 256;
            const int r = cc >> 3, off8 = (cc & 7) * 8;
            kr[p] = *(const uint4*)(k_bf + bh_nd + (size_t)(kt * 64 + r) * HD + off8);
            vr[p] = *(const uint4*)(v_th + bh_dn + (size_t)r * NSEQ + kt * 64 + off8);
        }
    };
    auto store_kv = [&](int st) {
        #pragma unroll
        for (int p = 0; p < 2; p++) {
            const int cc = t + p * 256;
            const int r = cc >> 3, off8 = (cc & 7) * 8;
            *(uint4*)&Ks[st][r * KVP + off8] = kr[p];
            *(uint4*)&Vs[st][r * KVP + off8] = vr[p];
        }
    };

    const bf16x8 ones = {(short)0x3F80, (short)0x3F80, (short)0x3F80, (short)0x3F80,
                         (short)0x3F80, (short)0x3F80, (short)0x3F80, (short)0x3F80};

    f32x4 o_acc[2][4], l_acc[2];
    #pragma unroll
    for (int mf = 0; mf < 2; mf++) {
        l_acc[mf] = (f32x4){0.f, 0.f, 0.f, 0.f};
        #pragma unroll
        for (int dt = 0; dt < 4; dt++) o_acc[mf][dt] = (f32x4){0.f, 0.f, 0.f, 0.f};
    }

    load_kv(0);
    store_kv(0);
    for (int kt = 0; kt < 16; kt++) {
        __syncthreads();                  // stage (kt&1) visible
        if (kt < 15) load_kv(kt + 1);     // prefetch next tile into VGPRs
        const unsigned short* K = Ks[kt & 1];
        const unsigned short* V = Vs[kt & 1];

        // ---- S = Q K^T (single plane), p = exp2(s), store P (bf16 RTN) ----
        #pragma unroll
        for (int nt = 0; nt < 4; nt++) {
            bf16x8 kb[2];
            #pragma unroll
            for (int ks = 0; ks < 2; ks++)
                kb[ks] = *(const bf16x8*)&K[(nt * 16 + l15) * KVP + ks * 32 + quad * 8];
            #pragma unroll
            for (int mf = 0; mf < 2; mf++) {
                f32x4 s = (f32x4){0.f, 0.f, 0.f, 0.f};
                s = MFMA16(qf[mf][0], kb[0], s);
                s = MFMA16(qf[mf][1], kb[1], s);
                const int prow_b = w * 32 + mf * 16 + quad * 4;
                const int col = nt * 16 + l15;
                #pragma unroll
                for (int r = 0; r < 4; r++) {
                    const int prow = prow_b + r;
                    Ps[prow * 64 + ((((col >> 3) ^ (prow & 7)) << 3) | (col & 7))] =
                        bf16_rtn(exp2f(s[r]));
                }
            }
        }

        // ---- O += P V, l += P 1 (P wave-private: no barrier) ----
        bf16x8 pf[2][2];
        #pragma unroll
        for (int mf = 0; mf < 2; mf++) {
            const int prow = w * 32 + mf * 16 + l15;
            #pragma unroll
            for (int ks = 0; ks < 2; ks++)
                pf[mf][ks] = *(const bf16x8*)&Ps[prow * 64 +
                                (((ks * 4 + quad) ^ (prow & 7)) << 3)];
            l_acc[mf] = MFMA16(pf[mf][0], ones, l_acc[mf]);
            l_acc[mf] = MFMA16(pf[mf][1], ones, l_acc[mf]);
        }
        #pragma unroll
        for (int dt = 0; dt < 4; dt++) {
            bf16x8 vh[2];
            #pragma unroll
            for (int ks = 0; ks < 2; ks++)
                vh[ks] = *(const bf16x8*)&V[(dt * 16 + l15) * KVP + ks * 32 + quad * 8];
            #pragma unroll
            for (int mf = 0; mf < 2; mf++) {
                o_acc[mf][dt] = MFMA16(pf[mf][0], vh[0], o_acc[mf][dt]);
                o_acc[mf][dt] = MFMA16(pf[mf][1], vh[1], o_acc[mf][dt]);
            }
        }
        if (kt < 15) store_kv((kt + 1) & 1);  // vmcnt wait lands post-MFMA
    }

    // ---- epilogue: normalize by l, single bf16 RTN plane for proj ----
    const int btq = bh >> 3, head = bh & 7;
    #pragma unroll
    for (int mf = 0; mf < 2; mf++)
        #pragma unroll
        for (int r = 0; r < 4; r++) {
            const float inv = 1.0f / l_acc[mf][r];
            const int row = qt * 128 + w * 32 + mf * 16 + quad * 4 + r;
            #pragma unroll
            for (int dt = 0; dt < 4; dt++) {
                const size_t off =
                    ((size_t)(btq * NSEQ + row)) * DMODEL + head * HD + dt * 16 + l15;
                o_bf[off] = bf16_rtn(o_acc[mf][dt][r] * inv);
            }
        }
}

// ---------------- Kernel 3: output projection (2-plane, pipelined) ----------------
__global__ __launch_bounds__(256, 3) void proj_mfma_kernel(
        const unsigned short* __restrict__ o_bf,
        const unsigned short* __restrict__ wo_bf,
        const float* __restrict__ b_out, float* __restrict__ out) {
    __shared__ __align__(16) char lds[32768];   // 2 x 16KB stages

    const int m0 = blockIdx.x * 128;
    const int f0 = blockIdx.y * 128;
    const int t = threadIdx.x;
    const int w = t >> 6, lane = t & 63, l15 = lane & 15, quad = lane >> 4;
    const int mw = (w & 1) * 64, nw = (w >> 1) * 64;

    f32x4 acc[4][4];
    #pragma unroll
    for (int mt = 0; mt < 4; mt++)
        #pragma unroll
        for (int nt = 0; nt < 4; nt++) acc[mt][nt] = (f32x4){0.f, 0.f, 0.f, 0.f};

    gemm_reg_pipe<2>(o_bf, o_bf, wo_bf, lds, m0, f0, t, acc);

    float bias_v[4];
    #pragma unroll
    for (int nt = 0; nt < 4; nt++) bias_v[nt] = b_out[f0 + nw + nt * 16 + l15];
    #pragma unroll
    for (int mt = 0; mt < 4; mt++)
        #pragma unroll
        for (int nt = 0; nt < 4; nt++)
            #pragma unroll
            for (int rr = 0; rr < 4; rr++) {
                const int m = m0 + mw + mt * 16 + quad * 4 + rr;
                out[(size_t)m * DMODEL + f0 + nw + nt * 16 + l15] =
                    acc[mt][nt][rr] + bias_v[nt];
            }
}

extern "C" void kernel_launch(void* const* d_in, const int* in_sizes, int n_in,
                              void* d_out, int out_size, void* d_ws, size_t ws_size,
                              hipStream_t stream) {
    const float* x  = (const float*)d_in[0];
    const float* wq = (const float*)d_in[1];
    const float* wo = (const float*)d_in[2];
    const float* bo = (const float*)d_in[3];
    float* out = (float*)d_out;

    const size_t per = (size_t)BH * NSEQ * HD;   // 8,388,608 elements
    unsigned short* x_hi = (unsigned short*)d_ws;   // reused as o_bf after qkv
    unsigned short* x_lo = x_hi + per;
    unsigned short* q_bf = x_lo + per;
    unsigned short* k_bf = q_bf + per;
    unsigned short* v_th = k_bf + per;
    unsigned short* wq_bf = v_th + per;                   // 786,432 els
    unsigned short* wo_bf = wq_bf + (size_t)F3 * DMODEL;  // 262,144 els (~82 MiB total)
    unsigned short* o_bf = x_hi;   // x dead after qkv

    split_kernel<<<dim3((int)(per / 1024)), 256, 0, stream>>>(x, x_hi, x_lo);
    cvt_kernel<<<dim3(F3 * DMODEL / 1024), 256, 0, stream>>>(wq, wq_bf);
    cvt_kernel<<<dim3(DMODEL * DMODEL / 1024), 256, 0, stream>>>(wo, wo_bf);
    qkv_mfma_kernel<<<dim3(NTOK / 128, F3 / 128), 256, 0, stream>>>(
        x_hi, x_lo, wq_bf, q_bf, k_bf, v_th);
    attn_kernel<<<dim3(8, BH), 256, 0, stream>>>(
        q_bf, k_bf, v_th, o_bf);
    proj_mfma_kernel<<<dim3(NTOK / 128, DMODEL / 128), 256, 0, stream>>>(
        o_bf, wo_bf, bo, out);
}